// Round 8
// baseline (101.271 us; speedup 1.0000x reference)
//
#include <hip/hip_runtime.h>

// ---------------------------------------------------------------------------
// Compile-time Clebsch-Gordan / real Wigner-3j machinery (mirrors reference).
// ---------------------------------------------------------------------------
namespace cg {

constexpr double fact(int n) {
  double r = 1.0;
  for (int i = 2; i <= n; ++i) r *= (double)i;
  return r;
}

constexpr double csqrt(double x) {
  if (x <= 0.0) return 0.0;
  double g = x < 1.0 ? 1.0 : x;
  for (int i = 0; i < 80; ++i) g = 0.5 * (g + x / g);
  return g;
}

struct cplx { double re, im; };
constexpr cplx cmul(cplx a, cplx b) {
  return cplx{a.re * b.re - a.im * b.im, a.re * b.im + a.im * b.re};
}

// Racah formula, e3nn convention: <j1 m1 j2 m2 | j3 m3>
constexpr double su2_cg(int j1, int m1, int j2, int m2, int j3, int m3) {
  if (m3 != m1 + m2) return 0.0;
  int vmin = -j1 + j2 + m3;
  if (-j1 + m1 > vmin) vmin = -j1 + m1;
  if (0 > vmin) vmin = 0;
  int vmax = j2 + j3 + m1;
  if (j3 - j1 + j2 < vmax) vmax = j3 - j1 + j2;
  if (j3 + m3 < vmax) vmax = j3 + m3;
  const double C = csqrt((2.0 * j3 + 1.0)
      * fact(j3 + j1 - j2) * fact(j3 - j1 + j2) * fact(j1 + j2 - j3)
      * fact(j3 + m3) * fact(j3 - m3)
      / (fact(j1 + j2 + j3 + 1) * fact(j1 - m1) * fact(j1 + m1)
         * fact(j2 - m2) * fact(j2 + m2)));
  double S = 0.0;
  for (int v = vmin; v <= vmax; ++v) {
    const double sgn = ((v + j2 + m2) & 1) ? -1.0 : 1.0;
    S += sgn * (fact(j2 + j3 + m1 - v) * fact(j1 - m1 + v)
         / (fact(v) * fact(j3 - j1 + j2 - v) * fact(j3 + m3 - v)
            * fact(v + j1 - j2 - m3)));
  }
  return C * S;
}

template <int L> struct QMat { cplx q[2 * L + 1][2 * L + 1]; };

// real -> complex SH change of basis (e3nn convention), rows m', cols m
template <int L>
constexpr QMat<L> make_q() {
  QMat<L> Q{};
  const double s = 1.0 / csqrt(2.0);
  for (int m = -L; m < 0; ++m) {
    Q.q[L + m][L - m] = cplx{s, 0.0};
    Q.q[L + m][L + m] = cplx{0.0, -s};
  }
  Q.q[L][L] = cplx{1.0, 0.0};
  for (int m = 1; m <= L; ++m) {
    const double sg = (m & 1) ? -1.0 : 1.0;
    Q.q[L + m][L + m] = cplx{sg * s, 0.0};
    Q.q[L + m][L - m] = cplx{0.0, sg * s};
  }
  cplx p{1.0, 0.0};                        // (-i)^L prefactor
  for (int t = 0; t < L; ++t) p = cmul(p, cplx{0.0, -1.0});
  for (int r = 0; r < 2 * L + 1; ++r)
    for (int c = 0; c < 2 * L + 1; ++c)
      Q.q[r][c] = cmul(p, Q.q[r][c]);
  return Q;
}

template <int L, int L1, int L2>
struct W3 { float t[2 * L + 1][2 * L1 + 1][2 * L2 + 1]; };

// real-basis wigner3j(L, L1, L2) * sqrt(2L+1), exactly as the reference CG dict
template <int L, int L1, int L2>
constexpr W3<L, L1, L2> wigner() {
  const QMat<L>  Q1 = make_q<L>();
  const QMat<L1> Q2 = make_q<L1>();
  const QMat<L2> Q3 = make_q<L2>();
  double C[2 * L + 1][2 * L1 + 1][2 * L2 + 1] = {};
  for (int m1 = -L; m1 <= L; ++m1)
    for (int m2 = -L1; m2 <= L1; ++m2) {
      const int m3 = m1 + m2;
      if (m3 >= -L2 && m3 <= L2)
        C[L + m1][L1 + m2][L2 + m3] = su2_cg(L, m1, L1, m2, L2, m3);
    }
  const double scale = csqrt(2.0 * L + 1.0) / csqrt(2.0 * L2 + 1.0);
  W3<L, L1, L2> R{};
  for (int j = 0; j < 2 * L + 1; ++j)
    for (int l = 0; l < 2 * L1 + 1; ++l)
      for (int m = 0; m < 2 * L2 + 1; ++m) {
        cplx acc{0.0, 0.0};
        for (int i = 0; i < 2 * L + 1; ++i) {
          const cplx q1 = Q1.q[i][j];
          if (q1.re == 0.0 && q1.im == 0.0) continue;
          for (int k = 0; k < 2 * L1 + 1; ++k) {
            const cplx q2 = Q2.q[k][l];
            if (q2.re == 0.0 && q2.im == 0.0) continue;
            const cplx q12 = cmul(q1, q2);
            for (int n = 0; n < 2 * L2 + 1; ++n) {
              const double c = C[i][k][n];
              if (c == 0.0) continue;
              const cplx q3c{Q3.q[n][m].re, -Q3.q[n][m].im};  // conj
              const cplx term = cmul(q12, q3c);
              acc.re += term.re * c;
              acc.im += term.im * c;
            }
          }
        }
        R.t[j][l][m] = (float)(acc.re * scale);
      }
  return R;
}

constexpr W3<0, 1, 1> W011 = wigner<0, 1, 1>();
constexpr W3<1, 1, 1> W111 = wigner<1, 1, 1>();
constexpr W3<2, 1, 1> W211 = wigner<2, 1, 1>();
constexpr W3<0, 2, 2> W022 = wigner<0, 2, 2>();
constexpr W3<1, 2, 2> W122 = wigner<1, 2, 2>();
constexpr W3<2, 2, 2> W222 = wigner<2, 2, 2>();
constexpr W3<3, 2, 2> W322 = wigner<3, 2, 2>();
constexpr W3<4, 2, 2> W422 = wigner<4, 2, 2>();

}  // namespace cg

// ---------------------------------------------------------------------------
// Kernel
// ---------------------------------------------------------------------------

template <int L, int L1, int L2>
__device__ __forceinline__ void contract(const cg::W3<L, L1, L2>& W,
                                         const float (&p)[2 * L1 + 1][2 * L2 + 1],
                                         float* __restrict__ o) {
#pragma unroll
  for (int i = 0; i < 2 * L + 1; ++i) {
    float acc = 0.0f;
#pragma unroll
    for (int j = 0; j < 2 * L1 + 1; ++j)
#pragma unroll
      for (int k = 0; k < 2 * L2 + 1; ++k) {
        const float c = W.t[i][j][k];
        if (c != 0.0f) acc = __builtin_fmaf(c, p[j][k], acc);
      }
    o[i] = acc;
  }
}

// in[] packing: 0 s0 | 1..3 a1 | 4..8 a2 | 9..11 ca | 12..14 cb | 15..19 cc
__device__ __forceinline__ void load_inputs(const float* __restrict__ f1,
                                            const float* __restrict__ f2,
                                            size_t r, int m, float (&in)[20]) {
  const float* F1 = f1 + r * 2304;
  const float* F2 = f2 + r * 2816;
  in[0] = F1[m];
#pragma unroll
  for (int j = 0; j < 3; ++j) in[1 + j] = F1[256 + m * 3 + j];
#pragma unroll
  for (int j = 0; j < 5; ++j) in[4 + j] = F1[1024 + m * 5 + j];
#pragma unroll
  for (int k = 0; k < 3; ++k) in[9 + k] = F2[m * 3 + k];
#pragma unroll
  for (int k = 0; k < 3; ++k) in[12 + k] = F2[768 + m * 3 + k];
#pragma unroll
  for (int k = 0; k < 5; ++k) in[15 + k] = F2[1536 + m * 5 + k];
}

// ZERO-BARRIER, wave-private, cross-row pipelined.
// 256-thread blocks; wave w owns channels [64w,64w+64) and a PRIVATE LDS
// region of 2368 floats (indices identical to the verified R5 kernel).
// Each block processes 4 consecutive rows; row i+1's global loads are issued
// BEFORE row i's scatter/readback/store so HBM latency hides under the DS +
// store phase. No __syncthreads: all LDS traffic is intra-wave (HW DS pipe is
// per-wave in-order); asm memory fences block compiler reordering across the
// scatter->readback and readback->next-scatter boundaries (the fence R4
// lacked; R5 proved the index math with syncthreads in place).
//
// wave-private region layout (output phase, 2368 floats):
//   p0 @0(192) | p1l0 @192(64) | p1l1 @256(192) | p1l2 @448(320)
//   p2l0 @768(64) | p2l1 @832(192) | p2l2 @1024(320) | p2l3 @1344(448)
//   p2l4 @1792(576)
__global__ __launch_bounds__(256) void tp_kernel(
    const float* __restrict__ f1, const float* __restrict__ f2,
    float* __restrict__ out, int B) {
  __shared__ __align__(16) float lds[9472];  // 4 wave-regions x 2368
  const int w = threadIdx.x >> 6;   // wave 0..3
  const int l = threadIdx.x & 63;   // lane 0..63
  const int m = 64 * w + l;         // channel 0..255
  float* Wr = lds + w * 2368;

  const int row0 = blockIdx.x * 4;
  if (row0 >= B) return;

  float in[20], in2[20];
  load_inputs(f1, f2, (size_t)row0, m, in);

#pragma unroll
  for (int i = 0; i < 4; ++i) {
    const int r = row0 + i;

    // ---------------- compute (all outputs into registers) --------------
    float r0[3];
#pragma unroll
    for (int k = 0; k < 3; ++k) r0[k] = in[0] * in[9 + k];

    float o0, o1[3], o2[5];
    {
      float p[3][3];
#pragma unroll
      for (int j = 0; j < 3; ++j)
#pragma unroll
        for (int k = 0; k < 3; ++k) p[j][k] = in[1 + j] * in[12 + k];
      contract<0, 1, 1>(cg::W011, p, &o0);
      contract<1, 1, 1>(cg::W111, p, o1);
      contract<2, 1, 1>(cg::W211, p, o2);
    }
    float q0, q1[3], q2[5], q3[7], q4[9];
    {
      float p[5][5];
#pragma unroll
      for (int j = 0; j < 5; ++j)
#pragma unroll
        for (int k = 0; k < 5; ++k) p[j][k] = in[4 + j] * in[15 + k];
      contract<0, 2, 2>(cg::W022, p, &q0);
      contract<1, 2, 2>(cg::W122, p, q1);
      contract<2, 2, 2>(cg::W222, p, q2);
      contract<3, 2, 2>(cg::W322, p, q3);
      contract<4, 2, 2>(cg::W422, p, q4);
    }

    // ---- issue next row's loads now: latency hides under DS + stores ----
    if (i < 3 && r + 1 < B) load_inputs(f1, f2, (size_t)(r + 1), m, in2);

    // ---------------- scatter into private region (output layout) -------
#pragma unroll
    for (int k = 0; k < 3; ++k) Wr[l * 3 + k] = r0[k];
    Wr[192 + l] = o0;
#pragma unroll
    for (int k = 0; k < 3; ++k) Wr[256 + l * 3 + k] = o1[k];
#pragma unroll
    for (int k = 0; k < 5; ++k) Wr[448 + l * 5 + k] = o2[k];
    Wr[768 + l] = q0;
#pragma unroll
    for (int k = 0; k < 3; ++k) Wr[832 + l * 3 + k] = q1[k];
#pragma unroll
    for (int k = 0; k < 5; ++k) Wr[1024 + l * 5 + k] = q2[k];
#pragma unroll
    for (int k = 0; k < 7; ++k) Wr[1344 + l * 7 + k] = q3[k];
#pragma unroll
    for (int k = 0; k < 9; ++k) Wr[1792 + l * 9 + k] = q4[k];

    asm volatile("" ::: "memory");  // scatter visible before f4 readback

    // ---------------- store-out: per-wave contiguous f4 slices ----------
    {
      const float4* OF = reinterpret_cast<const float4*>(Wr);
      float4* D = reinterpret_cast<float4*>(out + (size_t)r * 9472);
      if (l < 48) D[48 * w + l] = OF[l];                           // p0   (48)
      if (l < 16) D[192 + 16 * w + l] = OF[48 + l];                // p1l0 (16)
      if (l < 48) D[256 + 48 * w + l] = OF[64 + l];                // p1l1 (48)
      D[448 + 80 * w + l] = OF[112 + l];                           // p1l2 (80)
      if (l < 16) D[448 + 80 * w + 64 + l] = OF[176 + l];
      if (l < 16) D[768 + 16 * w + l] = OF[192 + l];               // p2l0 (16)
      if (l < 48) D[832 + 48 * w + l] = OF[208 + l];               // p2l1 (48)
      D[1024 + 80 * w + l] = OF[256 + l];                          // p2l2 (80)
      if (l < 16) D[1024 + 80 * w + 64 + l] = OF[320 + l];
      D[1344 + 112 * w + l] = OF[336 + l];                         // p2l3 (112)
      if (l < 48) D[1344 + 112 * w + 64 + l] = OF[400 + l];
      D[1792 + 144 * w + l] = OF[448 + l];                         // p2l4 (144)
      D[1792 + 144 * w + 64 + l] = OF[512 + l];
      if (l < 16) D[1792 + 144 * w + 128 + l] = OF[576 + l];
    }

    asm volatile("" ::: "memory");  // readback done before next scatter

    if (i < 3) {
#pragma unroll
      for (int k = 0; k < 20; ++k) in[k] = in2[k];
    }
  }
}

extern "C" void kernel_launch(void* const* d_in, const int* in_sizes, int n_in,
                              void* d_out, int out_size, void* d_ws, size_t ws_size,
                              hipStream_t stream) {
  const float* f1 = (const float*)d_in[0];
  const float* f2 = (const float*)d_in[1];
  float* out = (float*)d_out;
  const int B = in_sizes[0] / 2304;  // 8192
  tp_kernel<<<(B + 3) / 4, 256, 0, stream>>>(f1, f2, out, B);
}

// Round 9
// 86.154 us; speedup vs baseline: 1.1755x; 1.1755x over previous
//
#include <hip/hip_runtime.h>

// ---------------------------------------------------------------------------
// Compile-time Clebsch-Gordan / real Wigner-3j machinery (mirrors reference).
// ---------------------------------------------------------------------------
namespace cg {

constexpr double fact(int n) {
  double r = 1.0;
  for (int i = 2; i <= n; ++i) r *= (double)i;
  return r;
}

constexpr double csqrt(double x) {
  if (x <= 0.0) return 0.0;
  double g = x < 1.0 ? 1.0 : x;
  for (int i = 0; i < 80; ++i) g = 0.5 * (g + x / g);
  return g;
}

struct cplx { double re, im; };
constexpr cplx cmul(cplx a, cplx b) {
  return cplx{a.re * b.re - a.im * b.im, a.re * b.im + a.im * b.re};
}

// Racah formula, e3nn convention: <j1 m1 j2 m2 | j3 m3>
constexpr double su2_cg(int j1, int m1, int j2, int m2, int j3, int m3) {
  if (m3 != m1 + m2) return 0.0;
  int vmin = -j1 + j2 + m3;
  if (-j1 + m1 > vmin) vmin = -j1 + m1;
  if (0 > vmin) vmin = 0;
  int vmax = j2 + j3 + m1;
  if (j3 - j1 + j2 < vmax) vmax = j3 - j1 + j2;
  if (j3 + m3 < vmax) vmax = j3 + m3;
  const double C = csqrt((2.0 * j3 + 1.0)
      * fact(j3 + j1 - j2) * fact(j3 - j1 + j2) * fact(j1 + j2 - j3)
      * fact(j3 + m3) * fact(j3 - m3)
      / (fact(j1 + j2 + j3 + 1) * fact(j1 - m1) * fact(j1 + m1)
         * fact(j2 - m2) * fact(j2 + m2)));
  double S = 0.0;
  for (int v = vmin; v <= vmax; ++v) {
    const double sgn = ((v + j2 + m2) & 1) ? -1.0 : 1.0;
    S += sgn * (fact(j2 + j3 + m1 - v) * fact(j1 - m1 + v)
         / (fact(v) * fact(j3 - j1 + j2 - v) * fact(j3 + m3 - v)
            * fact(v + j1 - j2 - m3)));
  }
  return C * S;
}

template <int L> struct QMat { cplx q[2 * L + 1][2 * L + 1]; };

// real -> complex SH change of basis (e3nn convention), rows m', cols m
template <int L>
constexpr QMat<L> make_q() {
  QMat<L> Q{};
  const double s = 1.0 / csqrt(2.0);
  for (int m = -L; m < 0; ++m) {
    Q.q[L + m][L - m] = cplx{s, 0.0};
    Q.q[L + m][L + m] = cplx{0.0, -s};
  }
  Q.q[L][L] = cplx{1.0, 0.0};
  for (int m = 1; m <= L; ++m) {
    const double sg = (m & 1) ? -1.0 : 1.0;
    Q.q[L + m][L + m] = cplx{sg * s, 0.0};
    Q.q[L + m][L - m] = cplx{0.0, sg * s};
  }
  cplx p{1.0, 0.0};                        // (-i)^L prefactor
  for (int t = 0; t < L; ++t) p = cmul(p, cplx{0.0, -1.0});
  for (int r = 0; r < 2 * L + 1; ++r)
    for (int c = 0; c < 2 * L + 1; ++c)
      Q.q[r][c] = cmul(p, Q.q[r][c]);
  return Q;
}

template <int L, int L1, int L2>
struct W3 { float t[2 * L + 1][2 * L1 + 1][2 * L2 + 1]; };

// real-basis wigner3j(L, L1, L2) * sqrt(2L+1), exactly as the reference CG dict
template <int L, int L1, int L2>
constexpr W3<L, L1, L2> wigner() {
  const QMat<L>  Q1 = make_q<L>();
  const QMat<L1> Q2 = make_q<L1>();
  const QMat<L2> Q3 = make_q<L2>();
  double C[2 * L + 1][2 * L1 + 1][2 * L2 + 1] = {};
  for (int m1 = -L; m1 <= L; ++m1)
    for (int m2 = -L1; m2 <= L1; ++m2) {
      const int m3 = m1 + m2;
      if (m3 >= -L2 && m3 <= L2)
        C[L + m1][L1 + m2][L2 + m3] = su2_cg(L, m1, L1, m2, L2, m3);
    }
  const double scale = csqrt(2.0 * L + 1.0) / csqrt(2.0 * L2 + 1.0);
  W3<L, L1, L2> R{};
  for (int j = 0; j < 2 * L + 1; ++j)
    for (int l = 0; l < 2 * L1 + 1; ++l)
      for (int m = 0; m < 2 * L2 + 1; ++m) {
        cplx acc{0.0, 0.0};
        for (int i = 0; i < 2 * L + 1; ++i) {
          const cplx q1 = Q1.q[i][j];
          if (q1.re == 0.0 && q1.im == 0.0) continue;
          for (int k = 0; k < 2 * L1 + 1; ++k) {
            const cplx q2 = Q2.q[k][l];
            if (q2.re == 0.0 && q2.im == 0.0) continue;
            const cplx q12 = cmul(q1, q2);
            for (int n = 0; n < 2 * L2 + 1; ++n) {
              const double c = C[i][k][n];
              if (c == 0.0) continue;
              const cplx q3c{Q3.q[n][m].re, -Q3.q[n][m].im};  // conj
              const cplx term = cmul(q12, q3c);
              acc.re += term.re * c;
              acc.im += term.im * c;
            }
          }
        }
        R.t[j][l][m] = (float)(acc.re * scale);
      }
  return R;
}

constexpr W3<0, 1, 1> W011 = wigner<0, 1, 1>();
constexpr W3<1, 1, 1> W111 = wigner<1, 1, 1>();
constexpr W3<2, 1, 1> W211 = wigner<2, 1, 1>();
constexpr W3<0, 2, 2> W022 = wigner<0, 2, 2>();
constexpr W3<1, 2, 2> W122 = wigner<1, 2, 2>();
constexpr W3<2, 2, 2> W222 = wigner<2, 2, 2>();
constexpr W3<3, 2, 2> W322 = wigner<3, 2, 2>();
constexpr W3<4, 2, 2> W422 = wigner<4, 2, 2>();

}  // namespace cg

// ---------------------------------------------------------------------------
// Kernel
// ---------------------------------------------------------------------------

typedef float f32x4 __attribute__((ext_vector_type(4)));

template <int L, int L1, int L2>
__device__ __forceinline__ void contract(const cg::W3<L, L1, L2>& W,
                                         const float (&p)[2 * L1 + 1][2 * L2 + 1],
                                         float* __restrict__ o) {
#pragma unroll
  for (int i = 0; i < 2 * L + 1; ++i) {
    float acc = 0.0f;
#pragma unroll
    for (int j = 0; j < 2 * L1 + 1; ++j)
#pragma unroll
      for (int k = 0; k < 2 * L2 + 1; ++k) {
        const float c = W.t[i][j][k];
        if (c != 0.0f) acc = __builtin_fmaf(c, p[j][k], acc);
      }
    o[i] = acc;
  }
}

// R6 structure + two independent residual-shavers:
//  (a) wave-private output staging (indices HW-verified in R5/R7): no
//      __syncthreads at all; an asm compiler fence orders scatter->readback
//      (DS pipe is per-wave in-order in HW; R7 proved correctness).
//  (b) nontemporal loads/stores: both streams are touched exactly once
//      (168 MB read, 310 MB written), so `nt` streams past L2 allocation.
// INPUT stays direct per-lane strided global loads (12-20 B/lane contiguous;
// input LDS staging measured net-negative in R2 vs R6).
//
// wave-private region layout (output phase, 2368 floats):
//   p0 @0(192) | p1l0 @192(64) | p1l1 @256(192) | p1l2 @448(320)
//   p2l0 @768(64) | p2l1 @832(192) | p2l2 @1024(320) | p2l3 @1344(448)
//   p2l4 @1792(576)
__global__ __launch_bounds__(256) void tp_kernel(
    const float* __restrict__ f1, const float* __restrict__ f2,
    float* __restrict__ out, int B) {
  __shared__ __align__(16) float lds[9472];  // 4 wave-regions x 2368 = 37.9 KB
  const int b = blockIdx.x;
  if (b >= B) return;
  const int w = threadIdx.x >> 6;   // wave 0..3
  const int l = threadIdx.x & 63;   // lane 0..63
  const int m = 64 * w + l;         // channel 0..255
  float* Wr = lds + w * 2368;

  const float* F1 = f1 + (size_t)b * 2304;
  const float* F2 = f2 + (size_t)b * 2816;

  // ---------------- direct input loads (nontemporal, contiguous/lane) ---
  const float s0 = __builtin_nontemporal_load(&F1[m]);
  float a1[3], a2[5], ca[3], cb[3], cc[5];
#pragma unroll
  for (int j = 0; j < 3; ++j) a1[j] = __builtin_nontemporal_load(&F1[256 + m * 3 + j]);
#pragma unroll
  for (int j = 0; j < 5; ++j) a2[j] = __builtin_nontemporal_load(&F1[1024 + m * 5 + j]);
#pragma unroll
  for (int k = 0; k < 3; ++k) ca[k] = __builtin_nontemporal_load(&F2[m * 3 + k]);
#pragma unroll
  for (int k = 0; k < 3; ++k) cb[k] = __builtin_nontemporal_load(&F2[768 + m * 3 + k]);
#pragma unroll
  for (int k = 0; k < 5; ++k) cc[k] = __builtin_nontemporal_load(&F2[1536 + m * 5 + k]);

  // ---------------- compute (all outputs into registers) ----------------
  float r0[3];
#pragma unroll
  for (int k = 0; k < 3; ++k) r0[k] = s0 * ca[k];

  float o0, o1[3], o2[5];
  {
    float p[3][3];
#pragma unroll
    for (int j = 0; j < 3; ++j)
#pragma unroll
      for (int k = 0; k < 3; ++k) p[j][k] = a1[j] * cb[k];
    contract<0, 1, 1>(cg::W011, p, &o0);
    contract<1, 1, 1>(cg::W111, p, o1);
    contract<2, 1, 1>(cg::W211, p, o2);
  }
  float q0, q1[3], q2[5], q3[7], q4[9];
  {
    float p[5][5];
#pragma unroll
    for (int j = 0; j < 5; ++j)
#pragma unroll
      for (int k = 0; k < 5; ++k) p[j][k] = a2[j] * cc[k];
    contract<0, 2, 2>(cg::W022, p, &q0);
    contract<1, 2, 2>(cg::W122, p, q1);
    contract<2, 2, 2>(cg::W222, p, q2);
    contract<3, 2, 2>(cg::W322, p, q3);
    contract<4, 2, 2>(cg::W422, p, q4);
  }

  // ---------------- scatter into wave-private region (output layout) ----
#pragma unroll
  for (int k = 0; k < 3; ++k) Wr[l * 3 + k] = r0[k];
  Wr[192 + l] = o0;
#pragma unroll
  for (int k = 0; k < 3; ++k) Wr[256 + l * 3 + k] = o1[k];
#pragma unroll
  for (int k = 0; k < 5; ++k) Wr[448 + l * 5 + k] = o2[k];
  Wr[768 + l] = q0;
#pragma unroll
  for (int k = 0; k < 3; ++k) Wr[832 + l * 3 + k] = q1[k];
#pragma unroll
  for (int k = 0; k < 5; ++k) Wr[1024 + l * 5 + k] = q2[k];
#pragma unroll
  for (int k = 0; k < 7; ++k) Wr[1344 + l * 7 + k] = q3[k];
#pragma unroll
  for (int k = 0; k < 9; ++k) Wr[1792 + l * 9 + k] = q4[k];

  asm volatile("" ::: "memory");  // order scatter before readback (per-wave)

  // ---------------- store-out: per-wave contiguous f4 slices (nt) -------
  {
    const f32x4* OF = reinterpret_cast<const f32x4*>(Wr);
    f32x4* D = reinterpret_cast<f32x4*>(out + (size_t)b * 9472);
    if (l < 48) __builtin_nontemporal_store(OF[l], &D[48 * w + l]);            // p0
    if (l < 16) __builtin_nontemporal_store(OF[48 + l], &D[192 + 16 * w + l]); // p1l0
    if (l < 48) __builtin_nontemporal_store(OF[64 + l], &D[256 + 48 * w + l]); // p1l1
    __builtin_nontemporal_store(OF[112 + l], &D[448 + 80 * w + l]);            // p1l2
    if (l < 16) __builtin_nontemporal_store(OF[176 + l], &D[448 + 80 * w + 64 + l]);
    if (l < 16) __builtin_nontemporal_store(OF[192 + l], &D[768 + 16 * w + l]); // p2l0
    if (l < 48) __builtin_nontemporal_store(OF[208 + l], &D[832 + 48 * w + l]); // p2l1
    __builtin_nontemporal_store(OF[256 + l], &D[1024 + 80 * w + l]);            // p2l2
    if (l < 16) __builtin_nontemporal_store(OF[320 + l], &D[1024 + 80 * w + 64 + l]);
    __builtin_nontemporal_store(OF[336 + l], &D[1344 + 112 * w + l]);           // p2l3
    if (l < 48) __builtin_nontemporal_store(OF[400 + l], &D[1344 + 112 * w + 64 + l]);
    __builtin_nontemporal_store(OF[448 + l], &D[1792 + 144 * w + l]);           // p2l4
    __builtin_nontemporal_store(OF[512 + l], &D[1792 + 144 * w + 64 + l]);
    if (l < 16) __builtin_nontemporal_store(OF[576 + l], &D[1792 + 144 * w + 128 + l]);
  }
}

extern "C" void kernel_launch(void* const* d_in, const int* in_sizes, int n_in,
                              void* d_out, int out_size, void* d_ws, size_t ws_size,
                              hipStream_t stream) {
  const float* f1 = (const float*)d_in[0];
  const float* f2 = (const float*)d_in[1];
  float* out = (float*)d_out;
  const int B = in_sizes[0] / 2304;  // 8192
  tp_kernel<<<B, 256, 0, stream>>>(f1, f2, out, B);
}

// Round 10
// 86.100 us; speedup vs baseline: 1.1762x; 1.0006x over previous
//
#include <hip/hip_runtime.h>

// ---------------------------------------------------------------------------
// Compile-time Clebsch-Gordan / real Wigner-3j machinery (mirrors reference).
// ---------------------------------------------------------------------------
namespace cg {

constexpr double fact(int n) {
  double r = 1.0;
  for (int i = 2; i <= n; ++i) r *= (double)i;
  return r;
}

constexpr double csqrt(double x) {
  if (x <= 0.0) return 0.0;
  double g = x < 1.0 ? 1.0 : x;
  for (int i = 0; i < 80; ++i) g = 0.5 * (g + x / g);
  return g;
}

struct cplx { double re, im; };
constexpr cplx cmul(cplx a, cplx b) {
  return cplx{a.re * b.re - a.im * b.im, a.re * b.im + a.im * b.re};
}

// Racah formula, e3nn convention: <j1 m1 j2 m2 | j3 m3>
constexpr double su2_cg(int j1, int m1, int j2, int m2, int j3, int m3) {
  if (m3 != m1 + m2) return 0.0;
  int vmin = -j1 + j2 + m3;
  if (-j1 + m1 > vmin) vmin = -j1 + m1;
  if (0 > vmin) vmin = 0;
  int vmax = j2 + j3 + m1;
  if (j3 - j1 + j2 < vmax) vmax = j3 - j1 + j2;
  if (j3 + m3 < vmax) vmax = j3 + m3;
  const double C = csqrt((2.0 * j3 + 1.0)
      * fact(j3 + j1 - j2) * fact(j3 - j1 + j2) * fact(j1 + j2 - j3)
      * fact(j3 + m3) * fact(j3 - m3)
      / (fact(j1 + j2 + j3 + 1) * fact(j1 - m1) * fact(j1 + m1)
         * fact(j2 - m2) * fact(j2 + m2)));
  double S = 0.0;
  for (int v = vmin; v <= vmax; ++v) {
    const double sgn = ((v + j2 + m2) & 1) ? -1.0 : 1.0;
    S += sgn * (fact(j2 + j3 + m1 - v) * fact(j1 - m1 + v)
         / (fact(v) * fact(j3 - j1 + j2 - v) * fact(j3 + m3 - v)
            * fact(v + j1 - j2 - m3)));
  }
  return C * S;
}

template <int L> struct QMat { cplx q[2 * L + 1][2 * L + 1]; };

// real -> complex SH change of basis (e3nn convention), rows m', cols m
template <int L>
constexpr QMat<L> make_q() {
  QMat<L> Q{};
  const double s = 1.0 / csqrt(2.0);
  for (int m = -L; m < 0; ++m) {
    Q.q[L + m][L - m] = cplx{s, 0.0};
    Q.q[L + m][L + m] = cplx{0.0, -s};
  }
  Q.q[L][L] = cplx{1.0, 0.0};
  for (int m = 1; m <= L; ++m) {
    const double sg = (m & 1) ? -1.0 : 1.0;
    Q.q[L + m][L + m] = cplx{sg * s, 0.0};
    Q.q[L + m][L - m] = cplx{0.0, sg * s};
  }
  cplx p{1.0, 0.0};                        // (-i)^L prefactor
  for (int t = 0; t < L; ++t) p = cmul(p, cplx{0.0, -1.0});
  for (int r = 0; r < 2 * L + 1; ++r)
    for (int c = 0; c < 2 * L + 1; ++c)
      Q.q[r][c] = cmul(p, Q.q[r][c]);
  return Q;
}

template <int L, int L1, int L2>
struct W3 { float t[2 * L + 1][2 * L1 + 1][2 * L2 + 1]; };

// real-basis wigner3j(L, L1, L2) * sqrt(2L+1), exactly as the reference CG dict
template <int L, int L1, int L2>
constexpr W3<L, L1, L2> wigner() {
  const QMat<L>  Q1 = make_q<L>();
  const QMat<L1> Q2 = make_q<L1>();
  const QMat<L2> Q3 = make_q<L2>();
  double C[2 * L + 1][2 * L1 + 1][2 * L2 + 1] = {};
  for (int m1 = -L; m1 <= L; ++m1)
    for (int m2 = -L1; m2 <= L1; ++m2) {
      const int m3 = m1 + m2;
      if (m3 >= -L2 && m3 <= L2)
        C[L + m1][L1 + m2][L2 + m3] = su2_cg(L, m1, L1, m2, L2, m3);
    }
  const double scale = csqrt(2.0 * L + 1.0) / csqrt(2.0 * L2 + 1.0);
  W3<L, L1, L2> R{};
  for (int j = 0; j < 2 * L + 1; ++j)
    for (int l = 0; l < 2 * L1 + 1; ++l)
      for (int m = 0; m < 2 * L2 + 1; ++m) {
        cplx acc{0.0, 0.0};
        for (int i = 0; i < 2 * L + 1; ++i) {
          const cplx q1 = Q1.q[i][j];
          if (q1.re == 0.0 && q1.im == 0.0) continue;
          for (int k = 0; k < 2 * L1 + 1; ++k) {
            const cplx q2 = Q2.q[k][l];
            if (q2.re == 0.0 && q2.im == 0.0) continue;
            const cplx q12 = cmul(q1, q2);
            for (int n = 0; n < 2 * L2 + 1; ++n) {
              const double c = C[i][k][n];
              if (c == 0.0) continue;
              const cplx q3c{Q3.q[n][m].re, -Q3.q[n][m].im};  // conj
              const cplx term = cmul(q12, q3c);
              acc.re += term.re * c;
              acc.im += term.im * c;
            }
          }
        }
        R.t[j][l][m] = (float)(acc.re * scale);
      }
  return R;
}

constexpr W3<0, 1, 1> W011 = wigner<0, 1, 1>();
constexpr W3<1, 1, 1> W111 = wigner<1, 1, 1>();
constexpr W3<2, 1, 1> W211 = wigner<2, 1, 1>();
constexpr W3<0, 2, 2> W022 = wigner<0, 2, 2>();
constexpr W3<1, 2, 2> W122 = wigner<1, 2, 2>();
constexpr W3<2, 2, 2> W222 = wigner<2, 2, 2>();
constexpr W3<3, 2, 2> W322 = wigner<3, 2, 2>();
constexpr W3<4, 2, 2> W422 = wigner<4, 2, 2>();

}  // namespace cg

// ---------------------------------------------------------------------------
// Kernel
// ---------------------------------------------------------------------------

typedef float f32x4 __attribute__((ext_vector_type(4)));

template <int L, int L1, int L2>
__device__ __forceinline__ void contract(const cg::W3<L, L1, L2>& W,
                                         const float (&p)[2 * L1 + 1][2 * L2 + 1],
                                         float* __restrict__ o) {
#pragma unroll
  for (int i = 0; i < 2 * L + 1; ++i) {
    float acc = 0.0f;
#pragma unroll
    for (int j = 0; j < 2 * L1 + 1; ++j)
#pragma unroll
      for (int k = 0; k < 2 * L2 + 1; ++k) {
        const float c = W.t[i][j][k];
        if (c != 0.0f) acc = __builtin_fmaf(c, p[j][k], acc);
      }
    o[i] = acc;
  }
}

// R8 structure + occupancy push:
//  - CHUNKED wave-private output staging: chunk A = p0..p2l2 (1344 floats
//    per wave), chunk B = p2l3+p2l4 (1024), reusing ONE 1344-float region
//    -> LDS 21.5 KB/block -> 7 blocks/CU by LDS.
//  - q3/q4 computed AFTER chunk A's store (only the 25 pair-2 products stay
//    live across it) -> lower peak VGPR liveness.
//  - __launch_bounds__(256, 6): request 6 waves/SIMD (VGPR <= ~84) -> 24
//    waves/CU. Hypothesis: residual 12% vs copy roofline is latency-hiding.
//  - Still ZERO barriers (wave-private DS + asm compiler fences; HW DS pipe
//    is per-wave in-order -- proven R7/R8), nontemporal loads/stores.
__global__ __launch_bounds__(256, 6) void tp_kernel(
    const float* __restrict__ f1, const float* __restrict__ f2,
    float* __restrict__ out, int B) {
  __shared__ __align__(16) float lds[5376];  // 4 wave-regions x 1344 = 21.5 KB
  const int b = blockIdx.x;
  if (b >= B) return;
  const int w = threadIdx.x >> 6;   // wave 0..3
  const int l = threadIdx.x & 63;   // lane 0..63
  const int m = 64 * w + l;         // channel 0..255
  float* Wr = lds + w * 1344;

  const float* F1 = f1 + (size_t)b * 2304;
  const float* F2 = f2 + (size_t)b * 2816;

  // ---------------- direct input loads (nontemporal, contiguous/lane) ---
  const float s0 = __builtin_nontemporal_load(&F1[m]);
  float a1[3], a2[5], ca[3], cb[3], cc[5];
#pragma unroll
  for (int j = 0; j < 3; ++j) a1[j] = __builtin_nontemporal_load(&F1[256 + m * 3 + j]);
#pragma unroll
  for (int j = 0; j < 5; ++j) a2[j] = __builtin_nontemporal_load(&F1[1024 + m * 5 + j]);
#pragma unroll
  for (int k = 0; k < 3; ++k) ca[k] = __builtin_nontemporal_load(&F2[m * 3 + k]);
#pragma unroll
  for (int k = 0; k < 3; ++k) cb[k] = __builtin_nontemporal_load(&F2[768 + m * 3 + k]);
#pragma unroll
  for (int k = 0; k < 5; ++k) cc[k] = __builtin_nontemporal_load(&F2[1536 + m * 5 + k]);

  // ---------------- compute chunk-A outputs -----------------------------
  float r0[3];
#pragma unroll
  for (int k = 0; k < 3; ++k) r0[k] = s0 * ca[k];

  float o0, o1[3], o2[5];
  {
    float p[3][3];
#pragma unroll
    for (int j = 0; j < 3; ++j)
#pragma unroll
      for (int k = 0; k < 3; ++k) p[j][k] = a1[j] * cb[k];
    contract<0, 1, 1>(cg::W011, p, &o0);
    contract<1, 1, 1>(cg::W111, p, o1);
    contract<2, 1, 1>(cg::W211, p, o2);
  }
  float p2m[5][5];  // pair-2 products: stay live across chunk-A store
#pragma unroll
  for (int j = 0; j < 5; ++j)
#pragma unroll
    for (int k = 0; k < 5; ++k) p2m[j][k] = a2[j] * cc[k];
  float q0, q1[3], q2[5];
  contract<0, 2, 2>(cg::W022, p2m, &q0);
  contract<1, 2, 2>(cg::W122, p2m, q1);
  contract<2, 2, 2>(cg::W222, p2m, q2);

  // ------- scatter chunk A into wave-private region (output layout) -----
  //   p0 @0(192) | p1l0 @192(64) | p1l1 @256(192) | p1l2 @448(320)
  //   p2l0 @768(64) | p2l1 @832(192) | p2l2 @1024(320)
#pragma unroll
  for (int k = 0; k < 3; ++k) Wr[l * 3 + k] = r0[k];
  Wr[192 + l] = o0;
#pragma unroll
  for (int k = 0; k < 3; ++k) Wr[256 + l * 3 + k] = o1[k];
#pragma unroll
  for (int k = 0; k < 5; ++k) Wr[448 + l * 5 + k] = o2[k];
  Wr[768 + l] = q0;
#pragma unroll
  for (int k = 0; k < 3; ++k) Wr[832 + l * 3 + k] = q1[k];
#pragma unroll
  for (int k = 0; k < 5; ++k) Wr[1024 + l * 5 + k] = q2[k];

  asm volatile("" ::: "memory");  // scatter A before readback A (per-wave)

  // ------- store chunk A: per-wave contiguous f4 slices (nt) ------------
  {
    const f32x4* OF = reinterpret_cast<const f32x4*>(Wr);
    f32x4* D = reinterpret_cast<f32x4*>(out + (size_t)b * 9472);
    if (l < 48) __builtin_nontemporal_store(OF[l], &D[48 * w + l]);            // p0
    if (l < 16) __builtin_nontemporal_store(OF[48 + l], &D[192 + 16 * w + l]); // p1l0
    if (l < 48) __builtin_nontemporal_store(OF[64 + l], &D[256 + 48 * w + l]); // p1l1
    __builtin_nontemporal_store(OF[112 + l], &D[448 + 80 * w + l]);            // p1l2
    if (l < 16) __builtin_nontemporal_store(OF[176 + l], &D[448 + 80 * w + 64 + l]);
    if (l < 16) __builtin_nontemporal_store(OF[192 + l], &D[768 + 16 * w + l]); // p2l0
    if (l < 48) __builtin_nontemporal_store(OF[208 + l], &D[832 + 48 * w + l]); // p2l1
    __builtin_nontemporal_store(OF[256 + l], &D[1024 + 80 * w + l]);            // p2l2
    if (l < 16) __builtin_nontemporal_store(OF[320 + l], &D[1024 + 80 * w + 64 + l]);
  }

  asm volatile("" ::: "memory");  // readback A done before scatter B (WAR)

  // ---------------- compute chunk-B outputs (deferred) ------------------
  float q3[7], q4[9];
  contract<3, 2, 2>(cg::W322, p2m, q3);
  contract<4, 2, 2>(cg::W422, p2m, q4);

  // ------- scatter chunk B: p2l3 @0(448) | p2l4 @448(576) ---------------
#pragma unroll
  for (int k = 0; k < 7; ++k) Wr[l * 7 + k] = q3[k];
#pragma unroll
  for (int k = 0; k < 9; ++k) Wr[448 + l * 9 + k] = q4[k];

  asm volatile("" ::: "memory");  // scatter B before readback B

  // ------- store chunk B (nt) -------------------------------------------
  {
    const f32x4* OF = reinterpret_cast<const f32x4*>(Wr);
    f32x4* D = reinterpret_cast<f32x4*>(out + (size_t)b * 9472);
    __builtin_nontemporal_store(OF[l], &D[1344 + 112 * w + l]);                 // p2l3
    if (l < 48) __builtin_nontemporal_store(OF[64 + l], &D[1344 + 112 * w + 64 + l]);
    __builtin_nontemporal_store(OF[112 + l], &D[1792 + 144 * w + l]);           // p2l4
    __builtin_nontemporal_store(OF[176 + l], &D[1792 + 144 * w + 64 + l]);
    if (l < 16) __builtin_nontemporal_store(OF[240 + l], &D[1792 + 144 * w + 128 + l]);
  }
}

extern "C" void kernel_launch(void* const* d_in, const int* in_sizes, int n_in,
                              void* d_out, int out_size, void* d_ws, size_t ws_size,
                              hipStream_t stream) {
  const float* f1 = (const float*)d_in[0];
  const float* f2 = (const float*)d_in[1];
  float* out = (float*)d_out;
  const int B = in_sizes[0] / 2304;  // 8192
  tp_kernel<<<B, 256, 0, stream>>>(f1, f2, out, B);
}